// Round 6
// baseline (2286.235 us; speedup 1.0000x reference)
//
#include <hip/hip_runtime.h>
#include <float.h>

// RVQ inference via MFMA: B=16, C=64, N=4096, Q=8, K=8192, fp32 in/out.
// bf16 hi/lo split distance GEMM (hh+hl+lh, fp32 acc) on mfma_f32_16x16x32_bf16.
// Round-6 deltas vs round-5 (which spilled ~500 MB: VGPR stuck at 128 vs ~200
// demand; Bh/Bl file spilled/reloaded every q):
//  - Wave split 2-way-k x 2-way-points: wave w scans codes [(w&1)*4096, +4096)
//    for 4 ptiles (64 points, w>>1). B-frag file halves to 64 VGPRs -> total
//    demand ~135 fits without spilling. Codebook streamed 2x (L2 has headroom).
//  - __launch_bounds__(256,1): hard VGPR budget 512, allocator allocates
//    demand instead of spilling to a 128-reg occupancy target.
//  - Packed index now 12 bits (4096 codes/wave); perturbation <= |s|*2^-12,
//    still far under the TAU=0.05 exact-fp32 rescore net.
// ws: shalf (QK f32) | WH (QKC bf16-hi u16) | WL (lo) | loss (f32).

typedef float f32x4 __attribute__((ext_vector_type(4)));
typedef short s16x8 __attribute__((ext_vector_type(8)));

constexpr int Bn=16, Cn=64, Nn=4096, Qn=8, Kn=8192;
constexpr int P=128;                    // points per block
constexpr int NBLK = Bn*Nn/P;           // 512 blocks = 2/CU
constexpr float TAU = 0.05f;            // rescore margin
constexpr size_t SH_F = (size_t)Qn*Kn;
constexpr size_t W_U  = (size_t)Qn*Kn*Cn;

union U8 { s16x8 v; unsigned short u[8]; };

__device__ __forceinline__ unsigned short bf_rtne(float x){
  unsigned int u = __float_as_uint(x);
  unsigned int r = (u + 0x7fffu + ((u>>16)&1u)) >> 16;
  return (unsigned short)r;
}

__global__ __launch_bounds__(256) void prep_kernel(const float* __restrict__ cb,
    float* __restrict__ shalf, unsigned short* __restrict__ WH,
    unsigned short* __restrict__ WL, float* __restrict__ loss){
  int r = blockIdx.x*256 + threadIdx.x;
  if (r==0) *loss = 0.f;
  const float* row = cb + (size_t)r*Cn;
  float sq = 0.f;
  for (int c=0;c<Cn;++c){
    float v = row[c]; sq = fmaf(v,v,sq);
    unsigned short h = bf_rtne(v);
    float hf = __uint_as_float((unsigned int)h<<16);
    unsigned short l = bf_rtne(v-hf);
    WH[(size_t)r*Cn+c]=h; WL[(size_t)r*Cn+c]=l;
  }
  shalf[r] = -0.5f*sq;
}

__global__ __launch_bounds__(256,1)
void rvq_kernel(
    const float* __restrict__ x, const float* __restrict__ cb,
    const float* __restrict__ shalf,
    const unsigned short* __restrict__ WH, const unsigned short* __restrict__ WL,
    float* __restrict__ out, float* __restrict__ loss_acc){
  __shared__ float4 RES4[P*16];          // res[p][4g..] at [p*16 + (g^(p&15))]
  __shared__ float  red_p1[4][64];       // packed (score|k12): [wave][point-in-half]
  __shared__ float  red_p2[4][64];
  __shared__ int    bk_sh[P];
  __shared__ float  lsum[4];

  const int tid  = threadIdx.x;
  const int wave = tid>>6, lane = tid&63;
  const int quad = lane>>4, l16 = lane&15;
  const int kh   = wave & 1;             // code half: [kh*4096, +4096)
  const int ph   = wave >> 1;            // point half: [ph*64, +64)
  const int b    = blockIdx.x>>5;
  const int n0   = (blockIdx.x&31)*P;

  { // ---- RES init from x[B,C,N] (coalesced over p) ----
    int p = tid & (P-1), hc = tid>>7;
    const float* xb = x + ((size_t)b*Cn)*Nn + n0 + p;
#pragma unroll
    for (int l=0;l<8;++l){
      int g = hc*8 + l;
      float4 v;
      v.x = xb[(size_t)(4*g+0)*Nn]; v.y = xb[(size_t)(4*g+1)*Nn];
      v.z = xb[(size_t)(4*g+2)*Nn]; v.w = xb[(size_t)(4*g+3)*Nn];
      RES4[p*16 + (g ^ (p&15))] = v;
    }
  }
  __syncthreads();

  float loss_pt = 0.f;

  for (int q=0;q<Qn;++q){
    const unsigned short* WHq = WH + (size_t)q*Kn*Cn;
    const unsigned short* WLq = WL + (size_t)q*Kn*Cn;
    const float* sqq = shalf + (size_t)q*Kn;

    // ---- B-frags: 4 ptiles x 2 ch-halves x hi/lo = 64 VGPRs, resident ----
    s16x8 Bh[4][2], Bl[4][2];
#pragma unroll
    for (int pt=0; pt<4; ++pt){
      int p = ph*64 + pt*16 + l16;
#pragma unroll
      for (int s=0;s<2;++s){
        int g0 = 8*s + quad*2;
        float4 ra = RES4[p*16 + ((g0  ) ^ (p&15))];
        float4 rb = RES4[p*16 + ((g0+1) ^ (p&15))];
        float f[8] = {ra.x,ra.y,ra.z,ra.w, rb.x,rb.y,rb.z,rb.w};
        U8 h, lo;
#pragma unroll
        for (int j=0;j<8;++j){
          unsigned short hu = bf_rtne(f[j]);
          float hf = __uint_as_float((unsigned int)hu<<16);
          h.u[j]=hu; lo.u[j]=bf_rtne(f[j]-hf);
        }
        Bh[pt][s]=h.v; Bl[pt][s]=lo.v;
      }
    }

    // ---- scan this wave's 4096-code half; packed top-2 per point ----
    float s1[4], s2[4];
#pragma unroll
    for (int pt=0;pt<4;++pt){ s1[pt]=-FLT_MAX; s2[pt]=-FLT_MAX; }

    int kb = kh*4096;
    const int kq = quad*4;
    s16x8 Ah0 = *(const s16x8*)(WHq + (size_t)(kb+l16)*Cn + quad*8);
    s16x8 Ah1 = *(const s16x8*)(WHq + (size_t)(kb+l16)*Cn + 32 + quad*8);
    s16x8 Al0 = *(const s16x8*)(WLq + (size_t)(kb+l16)*Cn + quad*8);
    s16x8 Al1 = *(const s16x8*)(WLq + (size_t)(kb+l16)*Cn + 32 + quad*8);
    f32x4 sv  = *(const f32x4*)(sqq + kb + kq);

    for (int kt=0; kt<256; ++kt){
      int nkb = (kt<255) ? kb+16 : kh*4096;   // prefetch next ktile (L2-hot)
      s16x8 nAh0 = *(const s16x8*)(WHq + (size_t)(nkb+l16)*Cn + quad*8);
      s16x8 nAh1 = *(const s16x8*)(WHq + (size_t)(nkb+l16)*Cn + 32 + quad*8);
      s16x8 nAl0 = *(const s16x8*)(WLq + (size_t)(nkb+l16)*Cn + quad*8);
      s16x8 nAl1 = *(const s16x8*)(WLq + (size_t)(nkb+l16)*Cn + 32 + quad*8);
      f32x4 nsv  = *(const f32x4*)(sqq + nkb + kq);

      const unsigned int kloc = (unsigned int)((kb & 4095) | kq); // 12-bit local

#pragma unroll
      for (int pp=0; pp<2; ++pp){
        const int p0 = 2*pp, p1 = 2*pp+1;
        f32x4 a0, a1;                          // C-init = -0.5|c|^2 via sv
        a0 = __builtin_amdgcn_mfma_f32_16x16x32_bf16(Ah0, Bh[p0][0], sv, 0,0,0);
        a1 = __builtin_amdgcn_mfma_f32_16x16x32_bf16(Ah0, Bh[p1][0], sv, 0,0,0);
        a0 = __builtin_amdgcn_mfma_f32_16x16x32_bf16(Ah0, Bl[p0][0], a0, 0,0,0);
        a1 = __builtin_amdgcn_mfma_f32_16x16x32_bf16(Ah0, Bl[p1][0], a1, 0,0,0);
        a0 = __builtin_amdgcn_mfma_f32_16x16x32_bf16(Al0, Bh[p0][0], a0, 0,0,0);
        a1 = __builtin_amdgcn_mfma_f32_16x16x32_bf16(Al0, Bh[p1][0], a1, 0,0,0);
        a0 = __builtin_amdgcn_mfma_f32_16x16x32_bf16(Ah1, Bh[p0][1], a0, 0,0,0);
        a1 = __builtin_amdgcn_mfma_f32_16x16x32_bf16(Ah1, Bh[p1][1], a1, 0,0,0);
        a0 = __builtin_amdgcn_mfma_f32_16x16x32_bf16(Ah1, Bl[p0][1], a0, 0,0,0);
        a1 = __builtin_amdgcn_mfma_f32_16x16x32_bf16(Ah1, Bl[p1][1], a1, 0,0,0);
        a0 = __builtin_amdgcn_mfma_f32_16x16x32_bf16(Al1, Bh[p0][1], a0, 0,0,0);
        a1 = __builtin_amdgcn_mfma_f32_16x16x32_bf16(Al1, Bh[p1][1], a1, 0,0,0);
#pragma unroll
        for (int r=0;r<4;++r){
          float pv0 = __uint_as_float((__float_as_uint(a0[r]) & 0xFFFFF000u)
                                      | (kloc + (unsigned)r));
          float pv1 = __uint_as_float((__float_as_uint(a1[r]) & 0xFFFFF000u)
                                      | (kloc + (unsigned)r));
          float n20 = __builtin_amdgcn_fmed3f(pv0, s1[p0], s2[p0]);
          s1[p0] = fmaxf(s1[p0], pv0); s2[p0] = n20;
          float n21 = __builtin_amdgcn_fmed3f(pv1, s1[p1], s2[p1]);
          s1[p1] = fmaxf(s1[p1], pv1); s2[p1] = n21;
        }
      }
      kb = nkb; Ah0=nAh0; Ah1=nAh1; Al0=nAl0; Al1=nAl1; sv=nsv;
    }

    // ---- cross-quad top-2 merge in packed domain ----
#pragma unroll
    for (int pt=0;pt<4;++pt){
#pragma unroll
      for (int m=16; m<=32; m<<=1){
        float o1 = __shfl_xor(s1[pt], m, 64);
        float o2 = __shfl_xor(s2[pt], m, 64);
        float n1 = fmaxf(s1[pt], o1);
        float n2 = fmaxf(fminf(s1[pt], o1), fmaxf(s2[pt], o2));
        s1[pt]=n1; s2[pt]=n2;
      }
      if (quad==0){
        red_p1[wave][pt*16 + l16] = s1[pt];
        red_p2[wave][pt*16 + l16] = s2[pt];
      }
    }
    __syncthreads();

    // ---- per-point merge of the 2 k-half waves + margin rescore ----
    if (tid < P){
      int ph2 = tid >> 6, pl = tid & 63;
      float S1 = red_p1[2*ph2][pl]; int W1 = 0;
      float S2 = red_p2[2*ph2][pl]; int W2 = 0;
      float o1 = red_p1[2*ph2+1][pl], o2 = red_p2[2*ph2+1][pl];
      if (o1 > S1){
        if (S1 > o2){ S2 = S1; W2 = W1; } else { S2 = o2; W2 = 1; }
        S1 = o1; W1 = 1;
      } else if (o1 > S2){ S2 = o1; W2 = 1; }
      int K1 = (W1<<12) | (int)(__float_as_uint(S1) & 4095u);
      int K2 = (W2<<12) | (int)(__float_as_uint(S2) & 4095u);
      if (S1 - S2 < TAU){   // near-tie: exact fp32 rescore of both candidates
        float d1 = sqq[K1], d2 = sqq[K2];
        const float4* r1 = (const float4*)(cb + ((size_t)q*Kn + K1)*Cn);
        const float4* r2 = (const float4*)(cb + ((size_t)q*Kn + K2)*Cn);
#pragma unroll
        for (int g=0; g<16; ++g){
          float4 rv = RES4[tid*16 + (g ^ (tid&15))];
          float4 c1 = r1[g], c2 = r2[g];
          d1=fmaf(rv.x,c1.x,d1); d1=fmaf(rv.y,c1.y,d1);
          d1=fmaf(rv.z,c1.z,d1); d1=fmaf(rv.w,c1.w,d1);
          d2=fmaf(rv.x,c2.x,d2); d2=fmaf(rv.y,c2.y,d2);
          d2=fmaf(rv.z,c2.z,d2); d2=fmaf(rv.w,c2.w,d2);
        }
        if ( (d2 > d1) || (d2==d1 && K2<K1) ) K1 = K2;
      }
      bk_sh[tid]=K1;
      out[(size_t)(Bn*Cn*Nn) + (size_t)(b*Nn + n0 + tid)*Qn + q] = (float)K1;
    }
    __syncthreads();

    // ---- residual update (exact fp32, winner row L2-hot) + loss ----
    {
      int p = tid & (P-1), hc = tid>>7;
      int bk = bk_sh[p];
      const float4* crow = (const float4*)(cb + ((size_t)q*Kn + bk)*Cn) + hc*8;
#pragma unroll
      for (int l=0;l<8;++l){
        int g = hc*8 + l;
        float4 v = crow[l];
        int idx = p*16 + (g ^ (p&15));
        float4 rv = RES4[idx];
        rv.x-=v.x; rv.y-=v.y; rv.z-=v.z; rv.w-=v.w;
        RES4[idx]=rv;
        loss_pt = fmaf(rv.x,rv.x,loss_pt); loss_pt = fmaf(rv.y,rv.y,loss_pt);
        loss_pt = fmaf(rv.z,rv.z,loss_pt); loss_pt = fmaf(rv.w,rv.w,loss_pt);
      }
    }
    __syncthreads();
  } // q

  // ---- quantized = x - final residual (coalesced over p) ----
  {
    int p = tid & (P-1), hc = tid>>7;
    const float* xb = x + ((size_t)b*Cn)*Nn + n0 + p;
    float*       ob = out + ((size_t)b*Cn)*Nn + n0 + p;
#pragma unroll
    for (int l=0;l<8;++l){
      int g = hc*8+l, c = 4*g;
      float4 rv = RES4[p*16 + (g ^ (p&15))];
      ob[(size_t)(c+0)*Nn] = xb[(size_t)(c+0)*Nn] - rv.x;
      ob[(size_t)(c+1)*Nn] = xb[(size_t)(c+1)*Nn] - rv.y;
      ob[(size_t)(c+2)*Nn] = xb[(size_t)(c+2)*Nn] - rv.z;
      ob[(size_t)(c+3)*Nn] = xb[(size_t)(c+3)*Nn] - rv.w;
    }
  }
  float s = loss_pt;
#pragma unroll
  for (int off=32; off>0; off>>=1) s += __shfl_down(s, off, 64);
  if (lane==0) lsum[wave]=s;
  __syncthreads();
  if (tid==0) atomicAdd(loss_acc, lsum[0]+lsum[1]+lsum[2]+lsum[3]);
}

__global__ void final_kernel(const float* __restrict__ loss_acc,
                             float* __restrict__ out){
  out[(size_t)Bn*Cn*Nn + (size_t)Bn*Nn*Qn] =
      loss_acc[0] * (1.0f / ((float)Qn * Bn * Nn * Cn));
}

extern "C" void kernel_launch(void* const* d_in, const int* in_sizes, int n_in,
                              void* d_out, int out_size, void* d_ws, size_t ws_size,
                              hipStream_t stream) {
  const float* x  = (const float*)d_in[0];
  const float* cb = (const float*)d_in[1];
  float* out = (float*)d_out;
  float* ws  = (float*)d_ws;

  float* shalf = ws;
  unsigned short* WH = (unsigned short*)(ws + SH_F);
  unsigned short* WL = WH + W_U;
  float* loss = (float*)(WL + W_U);

  hipLaunchKernelGGL(prep_kernel, dim3((Qn*Kn)/256), dim3(256), 0, stream,
                     cb, shalf, WH, WL, loss);
  hipLaunchKernelGGL(rvq_kernel, dim3(NBLK), dim3(256), 0, stream,
                     x, cb, shalf, WH, WL, out, loss);
  hipLaunchKernelGGL(final_kernel, dim3(1), dim3(1), 0, stream, loss, out);
}

// Round 7
// 1675.919 us; speedup vs baseline: 1.3642x; 1.3642x over previous
//
#include <hip/hip_runtime.h>
#include <float.h>

// RVQ inference via MFMA: B=16, C=64, N=4096, Q=8, K=8192, fp32 in/out.
// bf16 hi/lo split distance GEMM (hh+hl+lh, fp32 acc) on mfma_f32_16x16x32_bf16.
// Round-7 = round-5 compute structure + round-6 register policy:
//  - 8 ptiles x 4-way k-split: 48 MFMA per 5 A-loads per ktile (r6's 2-ptile
//    halving doubled exposed VMEM latency -> MfmaUtil 31%).
//  - __launch_bounds__(256,1): allocator meets ~200-VGPR demand instead of
//    pinning 128 and spilling (r4/r5 lost ~500 MB/dispatch to scratch; r6
//    proved (256,1) allocates demand with zero spills).
//  - Packed-index top-2 argmax (11-bit wave-local k in mantissa LSBs),
//    fmed3+fmax, TAU=0.05 exact-fp32 rescore net (passed r5/r6).
// ws: shalf (QK f32) | WH (QKC bf16-hi u16) | WL (lo) | loss (f32).

typedef float f32x4 __attribute__((ext_vector_type(4)));
typedef short s16x8 __attribute__((ext_vector_type(8)));

constexpr int Bn=16, Cn=64, Nn=4096, Qn=8, Kn=8192;
constexpr int P=128;                    // points per block
constexpr int NBLK = Bn*Nn/P;           // 512 blocks = 2/CU
constexpr float TAU = 0.05f;            // rescore margin
constexpr size_t SH_F = (size_t)Qn*Kn;
constexpr size_t W_U  = (size_t)Qn*Kn*Cn;

union U8 { s16x8 v; unsigned short u[8]; };

__device__ __forceinline__ unsigned short bf_rtne(float x){
  unsigned int u = __float_as_uint(x);
  unsigned int r = (u + 0x7fffu + ((u>>16)&1u)) >> 16;
  return (unsigned short)r;
}

__global__ __launch_bounds__(256) void prep_kernel(const float* __restrict__ cb,
    float* __restrict__ shalf, unsigned short* __restrict__ WH,
    unsigned short* __restrict__ WL, float* __restrict__ loss){
  int r = blockIdx.x*256 + threadIdx.x;
  if (r==0) *loss = 0.f;
  const float* row = cb + (size_t)r*Cn;
  float sq = 0.f;
  for (int c=0;c<Cn;++c){
    float v = row[c]; sq = fmaf(v,v,sq);
    unsigned short h = bf_rtne(v);
    float hf = __uint_as_float((unsigned int)h<<16);
    unsigned short l = bf_rtne(v-hf);
    WH[(size_t)r*Cn+c]=h; WL[(size_t)r*Cn+c]=l;
  }
  shalf[r] = -0.5f*sq;
}

__global__ __launch_bounds__(256,1)
void rvq_kernel(
    const float* __restrict__ x, const float* __restrict__ cb,
    const float* __restrict__ shalf,
    const unsigned short* __restrict__ WH, const unsigned short* __restrict__ WL,
    float* __restrict__ out, float* __restrict__ loss_acc){
  __shared__ float4 RES4[P*16];          // res[p][4g..] at [p*16 + (g^(p&15))]
  __shared__ float  red_p1[4][P];        // packed (score|k11) per wave
  __shared__ float  red_p2[4][P];
  __shared__ int    bk_sh[P];
  __shared__ float  lsum[4];

  const int tid  = threadIdx.x;
  const int wave = tid>>6, lane = tid&63;
  const int quad = lane>>4, l16 = lane&15;
  const int b    = blockIdx.x>>5;
  const int n0   = (blockIdx.x&31)*P;

  { // ---- RES init from x[B,C,N] (coalesced over p) ----
    int p = tid & (P-1), hc = tid>>7;
    const float* xb = x + ((size_t)b*Cn)*Nn + n0 + p;
#pragma unroll
    for (int l=0;l<8;++l){
      int g = hc*8 + l;
      float4 v;
      v.x = xb[(size_t)(4*g+0)*Nn]; v.y = xb[(size_t)(4*g+1)*Nn];
      v.z = xb[(size_t)(4*g+2)*Nn]; v.w = xb[(size_t)(4*g+3)*Nn];
      RES4[p*16 + (g ^ (p&15))] = v;
    }
  }
  __syncthreads();

  float loss_pt = 0.f;

  for (int q=0;q<Qn;++q){
    const unsigned short* WHq = WH + (size_t)q*Kn*Cn;
    const unsigned short* WLq = WL + (size_t)q*Kn*Cn;
    const float* sqq = shalf + (size_t)q*Kn;

    // ---- B-frags (residual) persistent: 8 ptiles x 2 Khalves x hi/lo ----
    s16x8 Bh[8][2], Bl[8][2];
#pragma unroll
    for (int pt=0; pt<8; ++pt){
      int p = pt*16 + l16;
#pragma unroll
      for (int s=0;s<2;++s){
        int g0 = 8*s + quad*2;
        float4 ra = RES4[p*16 + ((g0  ) ^ (p&15))];
        float4 rb = RES4[p*16 + ((g0+1) ^ (p&15))];
        float f[8] = {ra.x,ra.y,ra.z,ra.w, rb.x,rb.y,rb.z,rb.w};
        U8 h, lo;
#pragma unroll
        for (int j=0;j<8;++j){
          unsigned short hu = bf_rtne(f[j]);
          float hf = __uint_as_float((unsigned int)hu<<16);
          h.u[j]=hu; lo.u[j]=bf_rtne(f[j]-hf);
        }
        Bh[pt][s]=h.v; Bl[pt][s]=lo.v;
      }
    }

    // ---- scan this wave's 2048-code quarter; packed top-2 per point ----
    float s1[8], s2[8];
#pragma unroll
    for (int pt=0;pt<8;++pt){ s1[pt]=-FLT_MAX; s2[pt]=-FLT_MAX; }

    int kb = wave*2048;
    const int kq = quad*4;
    s16x8 Ah0 = *(const s16x8*)(WHq + (size_t)(kb+l16)*Cn + quad*8);
    s16x8 Ah1 = *(const s16x8*)(WHq + (size_t)(kb+l16)*Cn + 32 + quad*8);
    s16x8 Al0 = *(const s16x8*)(WLq + (size_t)(kb+l16)*Cn + quad*8);
    s16x8 Al1 = *(const s16x8*)(WLq + (size_t)(kb+l16)*Cn + 32 + quad*8);
    f32x4 sv  = *(const f32x4*)(sqq + kb + kq);

    for (int kt=0; kt<128; ++kt){
      int nkb = (kt<127) ? kb+16 : kb;        // prefetch next ktile (L2-hot)
      s16x8 nAh0 = *(const s16x8*)(WHq + (size_t)(nkb+l16)*Cn + quad*8);
      s16x8 nAh1 = *(const s16x8*)(WHq + (size_t)(nkb+l16)*Cn + 32 + quad*8);
      s16x8 nAl0 = *(const s16x8*)(WLq + (size_t)(nkb+l16)*Cn + quad*8);
      s16x8 nAl1 = *(const s16x8*)(WLq + (size_t)(nkb+l16)*Cn + 32 + quad*8);
      f32x4 nsv  = *(const f32x4*)(sqq + nkb + kq);

      const unsigned int kloc = (unsigned int)((kb & 2047) | kq); // 11-bit local

#pragma unroll
      for (int pp=0; pp<4; ++pp){
        const int p0 = 2*pp, p1 = 2*pp+1;
        f32x4 a0, a1;                          // C-init = -0.5|c|^2 via sv
        a0 = __builtin_amdgcn_mfma_f32_16x16x32_bf16(Ah0, Bh[p0][0], sv, 0,0,0);
        a1 = __builtin_amdgcn_mfma_f32_16x16x32_bf16(Ah0, Bh[p1][0], sv, 0,0,0);
        a0 = __builtin_amdgcn_mfma_f32_16x16x32_bf16(Ah0, Bl[p0][0], a0, 0,0,0);
        a1 = __builtin_amdgcn_mfma_f32_16x16x32_bf16(Ah0, Bl[p1][0], a1, 0,0,0);
        a0 = __builtin_amdgcn_mfma_f32_16x16x32_bf16(Al0, Bh[p0][0], a0, 0,0,0);
        a1 = __builtin_amdgcn_mfma_f32_16x16x32_bf16(Al0, Bh[p1][0], a1, 0,0,0);
        a0 = __builtin_amdgcn_mfma_f32_16x16x32_bf16(Ah1, Bh[p0][1], a0, 0,0,0);
        a1 = __builtin_amdgcn_mfma_f32_16x16x32_bf16(Ah1, Bh[p1][1], a1, 0,0,0);
        a0 = __builtin_amdgcn_mfma_f32_16x16x32_bf16(Ah1, Bl[p0][1], a0, 0,0,0);
        a1 = __builtin_amdgcn_mfma_f32_16x16x32_bf16(Ah1, Bl[p1][1], a1, 0,0,0);
        a0 = __builtin_amdgcn_mfma_f32_16x16x32_bf16(Al1, Bh[p0][1], a0, 0,0,0);
        a1 = __builtin_amdgcn_mfma_f32_16x16x32_bf16(Al1, Bh[p1][1], a1, 0,0,0);
#pragma unroll
        for (int r=0;r<4;++r){
          float pv0 = __uint_as_float((__float_as_uint(a0[r]) & 0xFFFFF800u)
                                      | (kloc + (unsigned)r));
          float pv1 = __uint_as_float((__float_as_uint(a1[r]) & 0xFFFFF800u)
                                      | (kloc + (unsigned)r));
          float n20 = __builtin_amdgcn_fmed3f(pv0, s1[p0], s2[p0]);
          s1[p0] = fmaxf(s1[p0], pv0); s2[p0] = n20;
          float n21 = __builtin_amdgcn_fmed3f(pv1, s1[p1], s2[p1]);
          s1[p1] = fmaxf(s1[p1], pv1); s2[p1] = n21;
        }
      }
      kb = nkb; Ah0=nAh0; Ah1=nAh1; Al0=nAl0; Al1=nAl1; sv=nsv;
    }

    // ---- cross-quad top-2 merge in packed domain ----
#pragma unroll
    for (int pt=0;pt<8;++pt){
#pragma unroll
      for (int m=16; m<=32; m<<=1){
        float o1 = __shfl_xor(s1[pt], m, 64);
        float o2 = __shfl_xor(s2[pt], m, 64);
        float n1 = fmaxf(s1[pt], o1);
        float n2 = fmaxf(fminf(s1[pt], o1), fmaxf(s2[pt], o2));
        s1[pt]=n1; s2[pt]=n2;
      }
      if (quad==0){
        int p = pt*16 + l16;
        red_p1[wave][p]=s1[pt]; red_p2[wave][p]=s2[pt];
      }
    }
    __syncthreads();

    // ---- per-point 4-wave merge (track wave origin) + margin rescore ----
    if (tid < P){
      float S1 = red_p1[0][tid]; int W1 = 0;
      float S2 = red_p2[0][tid]; int W2 = 0;
#pragma unroll
      for (int w=1; w<4; ++w){
        float o1 = red_p1[w][tid], o2 = red_p2[w][tid];
        if (o1 > S1){
          if (S1 > o2){ S2 = S1; W2 = W1; } else { S2 = o2; W2 = w; }
          S1 = o1; W1 = w;
        } else if (o1 > S2){ S2 = o1; W2 = w; }
      }
      int K1 = (W1<<11) | (int)(__float_as_uint(S1) & 2047u);
      int K2 = (W2<<11) | (int)(__float_as_uint(S2) & 2047u);
      if (S1 - S2 < TAU){   // near-tie: exact fp32 rescore of both candidates
        float d1 = sqq[K1], d2 = sqq[K2];
        const float4* r1 = (const float4*)(cb + ((size_t)q*Kn + K1)*Cn);
        const float4* r2 = (const float4*)(cb + ((size_t)q*Kn + K2)*Cn);
#pragma unroll
        for (int g=0; g<16; ++g){
          float4 rv = RES4[tid*16 + (g ^ (tid&15))];
          float4 c1 = r1[g], c2 = r2[g];
          d1=fmaf(rv.x,c1.x,d1); d1=fmaf(rv.y,c1.y,d1);
          d1=fmaf(rv.z,c1.z,d1); d1=fmaf(rv.w,c1.w,d1);
          d2=fmaf(rv.x,c2.x,d2); d2=fmaf(rv.y,c2.y,d2);
          d2=fmaf(rv.z,c2.z,d2); d2=fmaf(rv.w,c2.w,d2);
        }
        if ( (d2 > d1) || (d2==d1 && K2<K1) ) K1 = K2;
      }
      bk_sh[tid]=K1;
      out[(size_t)(Bn*Cn*Nn) + (size_t)(b*Nn + n0 + tid)*Qn + q] = (float)K1;
    }
    __syncthreads();

    // ---- residual update (exact fp32, winner row L2-hot) + loss ----
    {
      int p = tid & (P-1), hc = tid>>7;
      int bk = bk_sh[p];
      const float4* crow = (const float4*)(cb + ((size_t)q*Kn + bk)*Cn) + hc*8;
#pragma unroll
      for (int l=0;l<8;++l){
        int g = hc*8 + l;
        float4 v = crow[l];
        int idx = p*16 + (g ^ (p&15));
        float4 rv = RES4[idx];
        rv.x-=v.x; rv.y-=v.y; rv.z-=v.z; rv.w-=v.w;
        RES4[idx]=rv;
        loss_pt = fmaf(rv.x,rv.x,loss_pt); loss_pt = fmaf(rv.y,rv.y,loss_pt);
        loss_pt = fmaf(rv.z,rv.z,loss_pt); loss_pt = fmaf(rv.w,rv.w,loss_pt);
      }
    }
    __syncthreads();
  } // q

  // ---- quantized = x - final residual (coalesced over p) ----
  {
    int p = tid & (P-1), hc = tid>>7;
    const float* xb = x + ((size_t)b*Cn)*Nn + n0 + p;
    float*       ob = out + ((size_t)b*Cn)*Nn + n0 + p;
#pragma unroll
    for (int l=0;l<8;++l){
      int g = hc*8+l, c = 4*g;
      float4 rv = RES4[p*16 + (g ^ (p&15))];
      ob[(size_t)(c+0)*Nn] = xb[(size_t)(c+0)*Nn] - rv.x;
      ob[(size_t)(c+1)*Nn] = xb[(size_t)(c+1)*Nn] - rv.y;
      ob[(size_t)(c+2)*Nn] = xb[(size_t)(c+2)*Nn] - rv.z;
      ob[(size_t)(c+3)*Nn] = xb[(size_t)(c+3)*Nn] - rv.w;
    }
  }
  float s = loss_pt;
#pragma unroll
  for (int off=32; off>0; off>>=1) s += __shfl_down(s, off, 64);
  if (lane==0) lsum[wave]=s;
  __syncthreads();
  if (tid==0) atomicAdd(loss_acc, lsum[0]+lsum[1]+lsum[2]+lsum[3]);
}

__global__ void final_kernel(const float* __restrict__ loss_acc,
                             float* __restrict__ out){
  out[(size_t)Bn*Cn*Nn + (size_t)Bn*Nn*Qn] =
      loss_acc[0] * (1.0f / ((float)Qn * Bn * Nn * Cn));
}

extern "C" void kernel_launch(void* const* d_in, const int* in_sizes, int n_in,
                              void* d_out, int out_size, void* d_ws, size_t ws_size,
                              hipStream_t stream) {
  const float* x  = (const float*)d_in[0];
  const float* cb = (const float*)d_in[1];
  float* out = (float*)d_out;
  float* ws  = (float*)d_ws;

  float* shalf = ws;
  unsigned short* WH = (unsigned short*)(ws + SH_F);
  unsigned short* WL = WH + W_U;
  float* loss = (float*)(WL + W_U);

  hipLaunchKernelGGL(prep_kernel, dim3((Qn*Kn)/256), dim3(256), 0, stream,
                     cb, shalf, WH, WL, loss);
  hipLaunchKernelGGL(rvq_kernel, dim3(NBLK), dim3(256), 0, stream,
                     x, cb, shalf, WH, WL, out, loss);
  hipLaunchKernelGGL(final_kernel, dim3(1), dim3(1), 0, stream, loss, out);
}